// Round 4
// baseline (1269.849 us; speedup 1.0000x reference)
//
#include <hip/hip_runtime.h>
#include <hip/hip_bf16.h>

constexpr int Sq = 256;
constexpr int Hq = 768;

typedef __attribute__((ext_vector_type(4))) float f32x4;
typedef __attribute__((ext_vector_type(8))) short bf16x8;

__device__ __forceinline__ float bf2f(unsigned short u) {
  unsigned int x = ((unsigned int)u) << 16;
  float f;
  __builtin_memcpy(&f, &x, 4);
  return f;
}
__device__ __forceinline__ unsigned short f2bf(float f) {
  unsigned int x;
  __builtin_memcpy(&x, &f, 4);
  unsigned int lsb = (x >> 16) & 1u;
  x += 0x7fffu + lsb;  // round-to-nearest-even
  return (unsigned short)(x >> 16);
}

// For option b (within its group of 4), the k-th other option (ascending).
__device__ __forceinline__ int other_of(int b, int k) {
  int i = b & 3;
  int jl = k + (k >= i ? 1 : 0);
  return (b & ~3) + jl;
}

constexpr int LDP = 40;  // padded LDS K-stride (elements); 80B pitch keeps 16B align

// Stage [ROWS x 32] fp32 tile -> bf16 LDS (single rounding).
template <int ROWS>
__device__ __forceinline__ void stage_f32(const float* __restrict__ G, int lda, int kk,
                                          unsigned short* __restrict__ S, int tid) {
#pragma unroll
  for (int pp = 0; pp < ROWS / 32; ++pp) {
    int idx = tid + pp * 256;
    int row = idx >> 3;
    int c4 = (idx & 7) << 2;
    float4 v = *(const float4*)(G + (long)row * lda + kk + c4);
    ushort4 o;
    o.x = f2bf(v.x);
    o.y = f2bf(v.y);
    o.z = f2bf(v.z);
    o.w = f2bf(v.w);
    *(ushort4*)(&S[row * LDP + c4]) = o;
  }
}

// Stage [ROWS x 32] fp32 tile -> hi/lo bf16 LDS pair (split precision).
template <int ROWS>
__device__ __forceinline__ void stage_f32_split(const float* __restrict__ G, int lda, int kk,
                                                unsigned short* __restrict__ Sh,
                                                unsigned short* __restrict__ Sl, int tid) {
#pragma unroll
  for (int pp = 0; pp < ROWS / 32; ++pp) {
    int idx = tid + pp * 256;
    int row = idx >> 3;
    int c4 = (idx & 7) << 2;
    float4 v = *(const float4*)(G + (long)row * lda + kk + c4);
    ushort4 h, l;
    h.x = f2bf(v.x);
    l.x = f2bf(v.x - bf2f(h.x));
    h.y = f2bf(v.y);
    l.y = f2bf(v.y - bf2f(h.y));
    h.z = f2bf(v.z);
    l.z = f2bf(v.z - bf2f(h.z));
    h.w = f2bf(v.w);
    l.w = f2bf(v.w - bf2f(h.w));
    *(ushort4*)(&Sh[row * LDP + c4]) = h;
    *(ushort4*)(&Sl[row * LDP + c4]) = l;
  }
}

// Stage [ROWS x 32] bf16 tile -> bf16 LDS.
template <int ROWS>
__device__ __forceinline__ void stage_b16(const unsigned short* __restrict__ G, int lda, int kk,
                                          unsigned short* __restrict__ S, int tid) {
#pragma unroll
  for (int pp = 0; pp < ROWS / 64; ++pp) {
    int idx = tid + pp * 256;
    int row = idx >> 2;
    int c8 = (idx & 3) << 3;
    uint4 v = *(const uint4*)(G + (long)row * lda + kk + c8);
    *(uint4*)(&S[row * LDP + c8]) = v;
  }
}

// ---------------------------------------------------------------------------
// Standard tiled MFMA GEMM core: C[128x128] = A[128xK] * op(B). bf16 MFMA.
// ---------------------------------------------------------------------------
template <bool A_F32, bool B_F32, bool B_NK>
__device__ __forceinline__ void gemm_tile(const void* __restrict__ Av, int lda,
                                          const void* __restrict__ Bv, int ldb, int K,
                                          f32x4 acc[4][4]) {
  __shared__ unsigned short As[128 * LDP];
  __shared__ unsigned short Bs[128 * LDP];
  const int tid = threadIdx.x;
  const int lane = tid & 63;
  const int wid = tid >> 6;
  const int wr = (wid >> 1) << 6;
  const int wc = (wid & 1) << 6;
  const int q4 = lane >> 4;
  const int l16 = lane & 15;

#pragma unroll
  for (int mi = 0; mi < 4; ++mi)
#pragma unroll
    for (int ni = 0; ni < 4; ++ni) acc[mi][ni] = (f32x4){0.f, 0.f, 0.f, 0.f};

  for (int kk = 0; kk < K; kk += 32) {
    __syncthreads();
    if constexpr (A_F32)
      stage_f32<128>((const float*)Av, lda, kk, As, tid);
    else
      stage_b16<128>((const unsigned short*)Av, lda, kk, As, tid);
    if constexpr (!B_NK) {
      if constexpr (B_F32)
        stage_f32<128>((const float*)Bv, ldb, kk, Bs, tid);
      else
        stage_b16<128>((const unsigned short*)Bv, ldb, kk, Bs, tid);
    } else {
      const unsigned short* Bp = (const unsigned short*)Bv;
#pragma unroll
      for (int pp = 0; pp < 2; ++pp) {
        int idx = tid + pp * 256;
        int kr = idx >> 4;
        int n8 = (idx & 15) << 3;
        uint4 v = *(const uint4*)(Bp + (long)(kk + kr) * ldb + n8);
        unsigned short tmp[8];
        *(uint4*)tmp = v;
#pragma unroll
        for (int jj = 0; jj < 8; ++jj) Bs[(n8 + jj) * LDP + kr] = tmp[jj];
      }
    }
    __syncthreads();
    bf16x8 af[4], bfr[4];
#pragma unroll
    for (int mi = 0; mi < 4; ++mi)
      af[mi] = *(const bf16x8*)(&As[(wr + mi * 16 + l16) * LDP + (q4 << 3)]);
#pragma unroll
    for (int ni = 0; ni < 4; ++ni)
      bfr[ni] = *(const bf16x8*)(&Bs[(wc + ni * 16 + l16) * LDP + (q4 << 3)]);
#pragma unroll
    for (int mi = 0; mi < 4; ++mi)
#pragma unroll
      for (int ni = 0; ni < 4; ++ni)
        acc[mi][ni] =
            __builtin_amdgcn_mfma_f32_16x16x32_bf16(af[mi], bfr[ni], acc[mi][ni], 0, 0, 0);
  }
}

// Split-precision GEMM core: fp32 A,B staged as hi/lo bf16; 3 MFMA chains.
__device__ __forceinline__ void gemm_tile_split(const float* __restrict__ A, int lda,
                                                const float* __restrict__ B, int ldb, int K,
                                                f32x4 acc[4][4]) {
  __shared__ unsigned short Ah[128 * LDP], Al[128 * LDP];
  __shared__ unsigned short Bh[128 * LDP], Bl[128 * LDP];
  const int tid = threadIdx.x;
  const int lane = tid & 63;
  const int wid = tid >> 6;
  const int wr = (wid >> 1) << 6;
  const int wc = (wid & 1) << 6;
  const int q4 = lane >> 4;
  const int l16 = lane & 15;

#pragma unroll
  for (int mi = 0; mi < 4; ++mi)
#pragma unroll
    for (int ni = 0; ni < 4; ++ni) acc[mi][ni] = (f32x4){0.f, 0.f, 0.f, 0.f};

  for (int kk = 0; kk < K; kk += 32) {
    __syncthreads();
    stage_f32_split<128>(A, lda, kk, Ah, Al, tid);
    stage_f32_split<128>(B, ldb, kk, Bh, Bl, tid);
    __syncthreads();
    bf16x8 ah[4], al[4], bh[4], bl[4];
#pragma unroll
    for (int mi = 0; mi < 4; ++mi) {
      ah[mi] = *(const bf16x8*)(&Ah[(wr + mi * 16 + l16) * LDP + (q4 << 3)]);
      al[mi] = *(const bf16x8*)(&Al[(wr + mi * 16 + l16) * LDP + (q4 << 3)]);
    }
#pragma unroll
    for (int ni = 0; ni < 4; ++ni) {
      bh[ni] = *(const bf16x8*)(&Bh[(wc + ni * 16 + l16) * LDP + (q4 << 3)]);
      bl[ni] = *(const bf16x8*)(&Bl[(wc + ni * 16 + l16) * LDP + (q4 << 3)]);
    }
#pragma unroll
    for (int mi = 0; mi < 4; ++mi)
#pragma unroll
      for (int ni = 0; ni < 4; ++ni) {
        acc[mi][ni] =
            __builtin_amdgcn_mfma_f32_16x16x32_bf16(ah[mi], bh[ni], acc[mi][ni], 0, 0, 0);
        acc[mi][ni] =
            __builtin_amdgcn_mfma_f32_16x16x32_bf16(ah[mi], bl[ni], acc[mi][ni], 0, 0, 0);
        acc[mi][ni] =
            __builtin_amdgcn_mfma_f32_16x16x32_bf16(al[mi], bh[ni], acc[mi][ni], 0, 0, 0);
      }
  }
}

// C/D layout (m89-verified): col=lane&15, row=(lane>>4)*4+reg.
#define EPI_BEGIN()                                        \
  const int lane = threadIdx.x & 63;                       \
  const int wid = threadIdx.x >> 6;                        \
  const int wr = (wid >> 1) << 6, wc = (wid & 1) << 6;     \
  const int q4 = lane >> 4, l16 = lane & 15;               \
  _Pragma("unroll") for (int mi = 0; mi < 4; ++mi)         \
      _Pragma("unroll") for (int ni = 0; ni < 4; ++ni)

// ---------------------------------------------------------------------------
// K1: tp = p @ Wt^T + bt  (split precision, stored as hi/lo bf16 pair)
__global__ __launch_bounds__(256) void k_tp(const float* __restrict__ p,
                                            const float* __restrict__ Wt,
                                            const float* __restrict__ bt,
                                            unsigned short* __restrict__ tph,
                                            unsigned short* __restrict__ tpl) {
  const int bm = blockIdx.x * 128, bn = blockIdx.y * 128;
  f32x4 acc[4][4];
  gemm_tile_split(p + (long)bm * Hq, Hq, Wt + (long)bn * Hq, Hq, Hq, acc);
  const bool has_lo = (tpl != nullptr);
  EPI_BEGIN() {
    int col = bn + wc + ni * 16 + l16;
    float bv = bt[col];
#pragma unroll
    for (int r = 0; r < 4; ++r) {
      int row = bm + wr + mi * 16 + q4 * 4 + r;
      float v = acc[mi][ni][r] + bv;
      unsigned short h = f2bf(v);
      tph[(long)row * Hq + col] = h;
      if (has_lo) tpl[(long)row * Hq + col] = f2bf(v - bf2f(h));
    }
  }
}

// K2: pd = p @ Wd^T  (no bias; bd added in k_occ) -> bf16
__global__ __launch_bounds__(256) void k_pd(const float* __restrict__ p,
                                            const float* __restrict__ Wd,
                                            unsigned short* __restrict__ pd) {
  const int bm = blockIdx.x * 128, bn = blockIdx.y * 128;
  f32x4 acc[4][4];
  gemm_tile<true, true, false>(p + (long)bm * Hq, Hq, Wd + (long)bn * Hq, Hq, Hq, acc);
  EPI_BEGIN() {
    int col = bn + wc + ni * 16 + l16;
#pragma unroll
    for (int r = 0; r < 4; ++r) {
      int row = bm + wr + mi * 16 + q4 * 4 + r;
      pd[(long)row * Hq + col] = f2bf(acc[mi][ni][r]);
    }
  }
}

// ---------------------------------------------------------------------------
// K3 (fused): sm[b,k] = masked_softmax(p[b] @ tp[j]^T)  -> bf16 [384,256,256]
// Split-precision scores: p hi/lo (staged) x tp hi/lo (precomputed).
// Block: 128 rows x 256 cols. 4 waves: 2 row-groups x 2 col-halves.
// ---------------------------------------------------------------------------
__global__ __launch_bounds__(256, 1) void k_attsm(const float* __restrict__ p,
                                                  const unsigned short* __restrict__ tph,
                                                  const unsigned short* __restrict__ tpl,
                                                  const int* __restrict__ olen,
                                                  unsigned short* __restrict__ sm) {
  const int batch = blockIdx.y;
  const int b = batch / 3, k = batch % 3;
  const int j = other_of(b, k);
  const int bm = blockIdx.x * 128;
  const int len = olen[j] + 1;  // key length, 1..255
  const int tid = threadIdx.x;
  const int lane = tid & 63;
  const int wid = tid >> 6;
  const int wr = (wid >> 1) << 6;  // 0 or 64
  const int wc = (wid & 1) << 7;   // 0 or 128
  const int half = wid & 1;
  const int q4 = lane >> 4, l16 = lane & 15;
  const bool has_lo = (tpl != nullptr);

  __shared__ unsigned short Ah[128 * LDP], Al[128 * LDP];
  __shared__ unsigned short Bh[256 * LDP], Bl[256 * LDP];
  __shared__ float red[256];  // 128 rows x 2 column-halves

  const float* A = p + ((long)b * Sq + bm) * Hq;
  const unsigned short* Bph = tph + (long)j * Sq * Hq;
  const unsigned short* Bpl = has_lo ? tpl + (long)j * Sq * Hq : nullptr;

  f32x4 acc[4][8];
#pragma unroll
  for (int mi = 0; mi < 4; ++mi)
#pragma unroll
    for (int ni = 0; ni < 8; ++ni) acc[mi][ni] = (f32x4){0.f, 0.f, 0.f, 0.f};

  for (int kk = 0; kk < Hq; kk += 32) {
    __syncthreads();
    stage_f32_split<128>(A, Hq, kk, Ah, Al, tid);
    stage_b16<256>(Bph, Hq, kk, Bh, tid);
    if (has_lo) stage_b16<256>(Bpl, Hq, kk, Bl, tid);
    __syncthreads();
    bf16x8 ah[4], al[4];
#pragma unroll
    for (int mi = 0; mi < 4; ++mi) {
      ah[mi] = *(const bf16x8*)(&Ah[(wr + mi * 16 + l16) * LDP + (q4 << 3)]);
      al[mi] = *(const bf16x8*)(&Al[(wr + mi * 16 + l16) * LDP + (q4 << 3)]);
    }
#pragma unroll
    for (int ni = 0; ni < 8; ++ni) {
      bf16x8 bh = *(const bf16x8*)(&Bh[(wc + ni * 16 + l16) * LDP + (q4 << 3)]);
#pragma unroll
      for (int mi = 0; mi < 4; ++mi) {
        acc[mi][ni] = __builtin_amdgcn_mfma_f32_16x16x32_bf16(ah[mi], bh, acc[mi][ni], 0, 0, 0);
        acc[mi][ni] = __builtin_amdgcn_mfma_f32_16x16x32_bf16(al[mi], bh, acc[mi][ni], 0, 0, 0);
      }
      if (has_lo) {
        bf16x8 bl = *(const bf16x8*)(&Bl[(wc + ni * 16 + l16) * LDP + (q4 << 3)]);
#pragma unroll
        for (int mi = 0; mi < 4; ++mi)
          acc[mi][ni] = __builtin_amdgcn_mfma_f32_16x16x32_bf16(ah[mi], bl, acc[mi][ni], 0, 0, 0);
      }
    }
  }

  // ---- reference-faithful masked softmax, numerically stable ----
  // Reference: e = exp(score*mask - m) over ALL 256 (masked -> exp(-m));
  // zs = full sum; final = e/(su + 1e-13*zs) unmasked, 0 masked,
  // where su = sum of unmasked e. Compute su directly (all-positive, stable),
  // zs = su + (256-len)*exp(-m) (addition only - no cancellation).
  bool cm[8];
#pragma unroll
  for (int ni = 0; ni < 8; ++ni) cm[ni] = (wc + ni * 16 + l16) >= len;
#pragma unroll
  for (int mi = 0; mi < 4; ++mi)
#pragma unroll
    for (int ni = 0; ni < 8; ++ni)
      if (cm[ni]) acc[mi][ni] = (f32x4){0.f, 0.f, 0.f, 0.f};  // score*mask

  float rmax[4][4];
#pragma unroll
  for (int mi = 0; mi < 4; ++mi)
#pragma unroll
    for (int r = 0; r < 4; ++r) {
      float m = acc[mi][0][r];
#pragma unroll
      for (int ni = 1; ni < 8; ++ni) m = fmaxf(m, acc[mi][ni][r]);
#pragma unroll
      for (int off = 1; off <= 8; off <<= 1) m = fmaxf(m, __shfl_xor(m, off, 64));
      rmax[mi][r] = m;  // max over this col-half (includes masked zeros)
    }
  if (l16 == 0) {
#pragma unroll
    for (int mi = 0; mi < 4; ++mi)
#pragma unroll
      for (int r = 0; r < 4; ++r) red[(wr + mi * 16 + q4 * 4 + r) * 2 + half] = rmax[mi][r];
  }
  __syncthreads();
#pragma unroll
  for (int mi = 0; mi < 4; ++mi)
#pragma unroll
    for (int r = 0; r < 4; ++r) {
      int row = wr + mi * 16 + q4 * 4 + r;
      rmax[mi][r] = fmaxf(red[row * 2], red[row * 2 + 1]);
    }
  __syncthreads();  // red reads done before reuse

  // su = sum of exp over UNMASKED entries only (stable).
  float rsum[4][4];
#pragma unroll
  for (int mi = 0; mi < 4; ++mi)
#pragma unroll
    for (int r = 0; r < 4; ++r) rsum[mi][r] = 0.f;
#pragma unroll
  for (int mi = 0; mi < 4; ++mi)
#pragma unroll
    for (int ni = 0; ni < 8; ++ni)
#pragma unroll
      for (int r = 0; r < 4; ++r) {
        float e = __expf(acc[mi][ni][r] - rmax[mi][r]);
        acc[mi][ni][r] = e;
        if (!cm[ni]) rsum[mi][r] += e;
      }
#pragma unroll
  for (int mi = 0; mi < 4; ++mi)
#pragma unroll
    for (int r = 0; r < 4; ++r) {
#pragma unroll
      for (int off = 1; off <= 8; off <<= 1) rsum[mi][r] += __shfl_xor(rsum[mi][r], off, 64);
    }
  if (l16 == 0) {
#pragma unroll
    for (int mi = 0; mi < 4; ++mi)
#pragma unroll
      for (int r = 0; r < 4; ++r) red[(wr + mi * 16 + q4 * 4 + r) * 2 + half] = rsum[mi][r];
  }
  __syncthreads();

  const float nm = (float)(Sq - len);
  unsigned short* srow = sm + (long)batch * Sq * Sq;
#pragma unroll
  for (int mi = 0; mi < 4; ++mi)
#pragma unroll
    for (int r = 0; r < 4; ++r) {
      int row = wr + mi * 16 + q4 * 4 + r;
      float su = red[row * 2] + red[row * 2 + 1];        // unmasked sum (>=0)
      float em = __expf(-rmax[mi][r]);                   // masked entries' e
      float zs = su + nm * em;                           // full softmax denom
      float fs = 1.f / (su + 1e-13f * zs);               // stable renorm
      unsigned short* o = srow + (long)(bm + row) * Sq + wc + l16;
#pragma unroll
      for (int ni = 0; ni < 8; ++ni)
        o[ni * 16] = f2bf(cm[ni] ? 0.f : acc[mi][ni][r] * fs);
    }
}

// K4: occ[(b,s,k),:] = relu(sm[b,k] @ pd[j] + bd)   rows in (b,s,k) order
__global__ __launch_bounds__(256) void k_occ(const unsigned short* __restrict__ sm,
                                             const unsigned short* __restrict__ pd,
                                             const float* __restrict__ bd,
                                             unsigned short* __restrict__ occ) {
  const int batch = blockIdx.z;
  const int b = batch / 3, k = batch % 3;
  const int j = other_of(b, k);
  const int bm = blockIdx.x * 128, bn = blockIdx.y * 128;
  f32x4 acc[4][4];
  gemm_tile<false, false, true>(sm + (long)batch * Sq * Sq + (long)bm * Sq, Sq,
                                pd + (long)j * Sq * Hq + bn, Hq, Sq, acc);
  EPI_BEGIN() {
    int col = bn + wc + ni * 16 + l16;
    float bv = bd[col];
#pragma unroll
    for (int r = 0; r < 4; ++r) {
      int s = bm + wr + mi * 16 + q4 * 4 + r;
      occ[((long)(b * Sq + s) * 3 + k) * Hq + col] = f2bf(fmaxf(acc[mi][ni][r] + bv, 0.f));
    }
  }
}

// K5: oc = occ_flat[32768,2304] @ Wd3^T + bd3  -> bf16
__global__ __launch_bounds__(256) void k_oc(const unsigned short* __restrict__ occ,
                                            const float* __restrict__ Wd3,
                                            const float* __restrict__ bd3,
                                            unsigned short* __restrict__ oc) {
  const int bm = blockIdx.x * 128, bn = blockIdx.y * 128;
  f32x4 acc[4][4];
  gemm_tile<false, true, false>(occ + (long)bm * 3 * Hq, 3 * Hq, Wd3 + (long)bn * 3 * Hq, 3 * Hq,
                                3 * Hq, acc);
  EPI_BEGIN() {
    int col = bn + wc + ni * 16 + l16;
    float bv = bd3[col];
#pragma unroll
    for (int r = 0; r < 4; ++r) {
      int row = bm + wr + mi * 16 + q4 * 4 + r;
      oc[(long)row * Hq + col] = f2bf(acc[mi][ni][r] + bv);
    }
  }
}

// K6: g1 = oc @ W1^T + b1 + b2  -> bf16
__global__ __launch_bounds__(256) void k_g1(const unsigned short* __restrict__ oc,
                                            const float* __restrict__ W1,
                                            const float* __restrict__ b1,
                                            const float* __restrict__ b2,
                                            unsigned short* __restrict__ g1) {
  const int bm = blockIdx.x * 128, bn = blockIdx.y * 128;
  f32x4 acc[4][4];
  gemm_tile<false, true, false>(oc + (long)bm * Hq, Hq, W1 + (long)bn * Hq, Hq, Hq, acc);
  EPI_BEGIN() {
    int col = bn + wc + ni * 16 + l16;
    float bv = b1[col] + b2[col];
#pragma unroll
    for (int r = 0; r < 4; ++r) {
      int row = bm + wr + mi * 16 + q4 * 4 + r;
      g1[(long)row * Hq + col] = f2bf(acc[mi][ni][r] + bv);
    }
  }
}

// K7: mid = sigmoid(g1 + p @ W2^T); out = p*mid + oc*(1-mid)  (fp32 out)
__global__ __launch_bounds__(256) void k_out(const float* __restrict__ p,
                                             const float* __restrict__ W2,
                                             const unsigned short* __restrict__ g1,
                                             const unsigned short* __restrict__ oc,
                                             float* __restrict__ out) {
  const int bm = blockIdx.x * 128, bn = blockIdx.y * 128;
  f32x4 acc[4][4];
  gemm_tile<true, true, false>(p + (long)bm * Hq, Hq, W2 + (long)bn * Hq, Hq, Hq, acc);
  EPI_BEGIN() {
    int col = bn + wc + ni * 16 + l16;
#pragma unroll
    for (int r = 0; r < 4; ++r) {
      int row = bm + wr + mi * 16 + q4 * 4 + r;
      long idx = (long)row * Hq + col;
      float g = acc[mi][ni][r] + bf2f(g1[idx]);
      float mid = 1.f / (1.f + __expf(-g));
      float pv = p[idx];
      float ov = bf2f(oc[idx]);
      out[idx] = pv * mid + ov * (1.f - mid);
    }
  }
}

// ---------------------------------------------------------------------------
extern "C" void kernel_launch(void* const* d_in, const int* in_sizes, int n_in, void* d_out,
                              int out_size, void* d_ws, size_t ws_size, hipStream_t stream) {
  const float* p = (const float*)d_in[0];
  const int* olen = (const int*)d_in[1];
  const float* Wt = (const float*)d_in[2];
  const float* bt = (const float*)d_in[3];
  const float* Wd = (const float*)d_in[4];
  const float* bd = (const float*)d_in[5];
  const float* Wd3 = (const float*)d_in[6];
  const float* bd3 = (const float*)d_in[7];
  const float* W1 = (const float*)d_in[8];
  const float* b1 = (const float*)d_in[9];
  const float* W2 = (const float*)d_in[10];
  const float* b2 = (const float*)d_in[11];
  float* out = (float*)d_out;

  char* ws = (char*)d_ws;
  const long U = 50331648L;  // 48 MiB unit
  unsigned short *tph, *tpl, *pd, *sm, *occ, *oc, *g1;
  if (ws_size >= (size_t)(6 * U)) {
    // 288 MiB layout (full split precision for tp):
    //   tph[0,1U) tpl[1U,2U) live K1..K3; occ[0,3U) K4..K5; oc[3U,4U) K5..K7;
    //   sm[4U,5U) K3..K4 -> g1[4U,5U) K6..K7; pd[5U,6U) K2..K4.
    tph = (unsigned short*)(ws + 0 * U);
    tpl = (unsigned short*)(ws + 1 * U);
    occ = (unsigned short*)(ws + 0 * U);
    oc = (unsigned short*)(ws + 3 * U);
    sm = (unsigned short*)(ws + 4 * U);
    g1 = (unsigned short*)(ws + 4 * U);
    pd = (unsigned short*)(ws + 5 * U);
  } else {
    // 240 MiB fallback: drop tp_lo (p-split only in k_attsm).
    tph = (unsigned short*)(ws + 0 * U);
    tpl = nullptr;
    occ = (unsigned short*)(ws + 0 * U);
    oc = (unsigned short*)(ws + 3 * U);
    pd = (unsigned short*)(ws + 3 * U);  // pd K2..K4, oc K5..K7: disjoint lifetimes
    sm = (unsigned short*)(ws + 4 * U);
    g1 = (unsigned short*)(ws + 4 * U);
  }

  k_tp<<<dim3(256, 6), 256, 0, stream>>>(p, Wt, bt, tph, tpl);
  k_pd<<<dim3(256, 6), 256, 0, stream>>>(p, Wd, pd);
  k_attsm<<<dim3(2, 384), 256, 0, stream>>>(p, tph, tpl, olen, sm);
  k_occ<<<dim3(2, 6, 384), 256, 0, stream>>>(sm, pd, bd, occ);
  k_oc<<<dim3(256, 6), 256, 0, stream>>>(occ, Wd3, bd3, oc);
  k_g1<<<dim3(256, 6), 256, 0, stream>>>(oc, W1, b1, b2, g1);
  k_out<<<dim3(256, 6), 256, 0, stream>>>(p, W2, g1, oc, out);
}